// Round 4
// baseline (299.951 us; speedup 1.0000x reference)
//
#include <hip/hip_runtime.h>

#define NVOX 150000
#define BM 256
#define MTILES 586          // ceil(150000/256)
#define SROW 150016         // 586*256, column stride of h buffer
#define NCOL 320

typedef __attribute__((ext_vector_type(8))) short bf16x8;
typedef __attribute__((ext_vector_type(4))) float f32x4;
typedef __attribute__((ext_vector_type(4))) unsigned short us4;

__device__ __forceinline__ unsigned short f2bf(float f) {
    unsigned u = __builtin_bit_cast(unsigned, f);
    u += 0x7fffu + ((u >> 16) & 1u);
    return (unsigned short)(u >> 16);
}

__device__ __forceinline__ void gld16(const void* g, void* l) {
    __builtin_amdgcn_global_load_lds(
        (const __attribute__((address_space(1))) unsigned int*)g,
        (__attribute__((address_space(3))) unsigned int*)l, 16, 0, 0);
}

// ---------------- prep: features f32 -> bf16, x4 vectorized (+ zero row) ----------------
__global__ void prep_feat(const float* __restrict__ src, unsigned short* __restrict__ dst) {
    int i = blockIdx.x * 256 + threadIdx.x;
    if (i < NVOX * 16) {
        const float4 v = *(const float4*)(src + (size_t)i * 4);
        us4 o; o.x = f2bf(v.x); o.y = f2bf(v.y); o.z = f2bf(v.z); o.w = f2bf(v.w);
        *(us4*)(dst + (size_t)i * 4) = o;
    } else if (i < NVOX * 16 + 16) {
        us4 z; z.x = 0; z.y = 0; z.z = 0; z.w = 0;
        *(us4*)(dst + (size_t)i * 4) = z;   // zero row for invalid/pad gathers
    }
}

// ---- prep: W3[h][kk][c][o] f32 -> Bt[h*64+o][k=kk*64+c] bf16; zero stats ----
__global__ void prep_w3(const float* __restrict__ w3, unsigned short* __restrict__ bt,
                        float* __restrict__ stats) {
    int i = blockIdx.x * 256 + threadIdx.x;   // grid is exactly 184320 threads
    int h = i / 36864;
    int rem = i - h * 36864;
    int kk = rem >> 12;
    int c = (rem >> 6) & 63;
    int o = rem & 63;
    bt[(size_t)(h * 64 + o) * 576 + kk * 64 + c] = f2bf(w3[i]);
    if (i < 2 * NCOL) stats[i] = 0.f;
}

// ---------------- gather-GEMM: BM=256/BN=64, wave tile 64x64, A via global_load_lds,
// B direct global->reg (L1-resident, no LDS). MFMA:ds_read = 4:1. ----------------
__global__ __launch_bounds__(256, 3)
void gemm_kernel(const unsigned short* __restrict__ featB,
                 const unsigned short* __restrict__ Bt,
                 const int* __restrict__ nbr,
                 unsigned short* __restrict__ hbuf,
                 float* __restrict__ stats) {
    __shared__ __align__(16) char smem[44032];
    constexpr int IDX_OFF = 32768;   // 9*256 int byte-offsets (9216 B)
    constexpr int SRED_OFF = 41984;  // 4*4*16*2 floats (2048 B)

    // XCD swizzle: the 5 head-blocks of one mtile share bid%8 -> same XCD (A L2 reuse)
    int bid = blockIdx.x;
    int r = bid & 7, q = bid >> 3;
    int ntile = q % 5;
    int mtile = (q / 5) * 8 + r;
    if (mtile >= MTILES) return;
    int m0 = mtile * BM;
    int n0 = ntile * 64;

    int tid = threadIdx.x;
    int w = tid >> 6, lane = tid & 63;
    int quad = lane >> 4, m16 = lane & 15;

    // ---- stage neighbor byte-offset table: sIdx[kk*256 + row] = srow*128 ----
    for (int lin = tid; lin < 2304; lin += 256) {
        int kkq = lin >> 8, row = lin & 255;
        int v = (m0 + row < NVOX) ? nbr[(size_t)(m0 + row) * 9 + kkq] : -1;
        *(int*)(smem + IDX_OFF + lin * 4) = ((v < 0) ? NVOX : v) * 128;
    }
    __syncthreads();

    f32x4 acc[4][4];
#pragma unroll
    for (int mt = 0; mt < 4; ++mt)
#pragma unroll
        for (int nt = 0; nt < 4; ++nt)
            acc[mt][nt] = (f32x4){0.f, 0.f, 0.f, 0.f};

    const char* fb = (const char*)featB;
    const unsigned short* bb[4];
#pragma unroll
    for (int nt = 0; nt < 4; ++nt)
        bb[nt] = Bt + (size_t)(n0 + nt * 16 + m16) * 576 + quad * 8;

    char* sA = smem;   // chunk-major: sA + c16*4096 + row*16, c16 = ks*4+quad

    for (int kk = 0; kk < 9; ++kk) {
        // per-lane gather byte offsets for the 4 row-groups
        int off[4];
#pragma unroll
        for (int rg = 0; rg < 4; ++rg)
            off[rg] = *(const int*)(smem + IDX_OFF + (kk * 256 + rg * 64 + lane) * 4);
        // A: 8 async 1KB gathers; wave w owns 16B chunks c16 = 2w, 2w+1
#pragma unroll
        for (int cc = 0; cc < 2; ++cc) {
            int c16 = w * 2 + cc;
#pragma unroll
            for (int rg = 0; rg < 4; ++rg)
                gld16(fb + off[rg] + c16 * 16, sA + c16 * 4096 + rg * 1024 + lane * 16);
        }
        // B: direct to regs (16 rows x 16B per load, L1-resident working set 8KB/kk)
        bf16x8 bfr[2][4];
#pragma unroll
        for (int ks = 0; ks < 2; ++ks)
#pragma unroll
            for (int nt = 0; nt < 4; ++nt)
                bfr[ks][nt] = *(const bf16x8*)(bb[nt] + kk * 64 + ks * 32);
        __syncthreads();   // vmcnt(0)+barrier: A staged block-wide
        // ---- compute: 8 ds_read_b128 + 32 MFMA ----
        bf16x8 af[2][4];
#pragma unroll
        for (int ks = 0; ks < 2; ++ks)
#pragma unroll
            for (int mt = 0; mt < 4; ++mt)
                af[ks][mt] = *(const bf16x8*)(sA + (ks * 4 + quad) * 4096 +
                                              (w * 64 + mt * 16 + m16) * 16);
#pragma unroll
        for (int ks = 0; ks < 2; ++ks)
#pragma unroll
            for (int mt = 0; mt < 4; ++mt)
#pragma unroll
                for (int nt = 0; nt < 4; ++nt)
                    acc[mt][nt] = __builtin_amdgcn_mfma_f32_16x16x32_bf16(
                        af[ks][mt], bfr[ks][nt], acc[mt][nt], 0, 0, 0);
        __syncthreads();   // compute done before restaging
    }

    // ---- epilogue 1: column-major LDS tile (stride 528B, 16B-aligned), coalesced stores ----
    unsigned short* sOut = (unsigned short*)smem;   // 64 cols x 264 ushorts = 33792 B
#pragma unroll
    for (int mt = 0; mt < 4; ++mt) {
#pragma unroll
        for (int nt = 0; nt < 4; ++nt) {
            int col = nt * 16 + m16;
            int row = w * 64 + mt * 16 + quad * 4;
            f32x4 v = acc[mt][nt];
            unsigned lo = (unsigned)f2bf(v.x) | ((unsigned)f2bf(v.y) << 16);
            unsigned hi = (unsigned)f2bf(v.z) | ((unsigned)f2bf(v.w) << 16);
            uint2 pk; pk.x = lo; pk.y = hi;
            *(uint2*)(sOut + col * 264 + row) = pk;
        }
    }
    __syncthreads();
#pragma unroll
    for (int it = 0; it < 8; ++it) {
        int col = it * 8 + (tid >> 5);
        int l32 = tid & 31;
        uint4 v = *(const uint4*)(sOut + col * 264 + l32 * 8);
        *(uint4*)(hbuf + (size_t)(n0 + col) * SROW + m0 + l32 * 8) = v;  // 512B runs
    }

    // ---- epilogue 2: BN statistics (pad/invalid rows are exact zeros) ----
    float s[4], ss[4];
#pragma unroll
    for (int nt = 0; nt < 4; ++nt) {
        float a = 0.f, b = 0.f;
#pragma unroll
        for (int mt = 0; mt < 4; ++mt) {
            f32x4 v = acc[mt][nt];
            a += v.x + v.y + v.z + v.w;
            b += v.x * v.x + v.y * v.y + v.z * v.z + v.w * v.w;
        }
        s[nt] = a; ss[nt] = b;
        s[nt] += __shfl_xor(s[nt], 16); s[nt] += __shfl_xor(s[nt], 32);
        ss[nt] += __shfl_xor(ss[nt], 16); ss[nt] += __shfl_xor(ss[nt], 32);
    }
    float* sRed = (float*)(smem + SRED_OFF);
    if (quad == 0) {
#pragma unroll
        for (int nt = 0; nt < 4; ++nt) {
            sRed[((w * 4 + nt) * 16 + m16) * 2 + 0] = s[nt];
            sRed[((w * 4 + nt) * 16 + m16) * 2 + 1] = ss[nt];
        }
    }
    __syncthreads();
    if (tid < 64) {
        int nt = tid >> 4, c = tid & 15;
        float a = 0.f, b = 0.f;
#pragma unroll
        for (int ww = 0; ww < 4; ++ww) {
            a += sRed[((ww * 4 + nt) * 16 + c) * 2 + 0];
            b += sRed[((ww * 4 + nt) * 16 + c) * 2 + 1];
        }
        atomicAdd(&stats[n0 + tid], a);
        atomicAdd(&stats[NCOL + n0 + tid], b);
    }
}

// ------- pass 2: BN + ReLU + 1x1 conv; thread = (row-pair, head), h wave-uniform -------
__global__ void head_kernel(const unsigned short* __restrict__ hbuf,
                            const float* __restrict__ stats,
                            const float* __restrict__ gamma, const float* __restrict__ beta,
                            const float* __restrict__ W1_0, const float* __restrict__ W1_1,
                            const float* __restrict__ W1_2, const float* __restrict__ W1_3,
                            const float* __restrict__ W1_4,
                            const float* __restrict__ b1_0, const float* __restrict__ b1_1,
                            const float* __restrict__ b1_2, const float* __restrict__ b1_3,
                            const float* __restrict__ b1_4,
                            float* __restrict__ out) {
    __shared__ float sScale[NCOL], sShift[NCOL], sW1[NCOL * 3], sB1[16];
    int tid = threadIdx.x;
    for (int c = tid; c < NCOL; c += 256) {
        float mean = stats[c] * (1.f / (float)NVOX);
        float var = stats[NCOL + c] * (1.f / (float)NVOX) - mean * mean;
        float inv = rsqrtf(var + 1e-5f);
        float sc = inv * gamma[c];
        sScale[c] = sc;
        sShift[c] = beta[c] - mean * sc;
    }
    for (int i = tid; i < 192; i += 256) { int cc = i / 3, jj = i - cc * 3; sW1[0 * 192 + i] = W1_0[cc * 3 + jj]; }
    for (int i = tid; i < 192; i += 256) { int cc = i / 3, jj = i - cc * 3; sW1[1 * 192 + i] = (jj < 2) ? W1_1[cc * 2 + jj] : 0.f; }
    for (int i = tid; i < 192; i += 256) { int cc = i / 3, jj = i - cc * 3; sW1[2 * 192 + i] = (jj < 1) ? W1_2[cc] : 0.f; }
    for (int i = tid; i < 192; i += 256) { int cc = i / 3, jj = i - cc * 3; sW1[3 * 192 + i] = W1_3[cc * 3 + jj]; }
    for (int i = tid; i < 192; i += 256) { int cc = i / 3, jj = i - cc * 3; sW1[4 * 192 + i] = (jj < 2) ? W1_4[cc * 2 + jj] : 0.f; }
    if (tid == 0) {
        sB1[0] = b1_0[0]; sB1[1] = b1_0[1]; sB1[2] = b1_0[2];
        sB1[3] = b1_1[0]; sB1[4] = b1_1[1]; sB1[5] = 0.f;
        sB1[6] = b1_2[0]; sB1[7] = 0.f;    sB1[8] = 0.f;
        sB1[9] = b1_3[0]; sB1[10] = b1_3[1]; sB1[11] = b1_3[2];
        sB1[12] = b1_4[0]; sB1[13] = b1_4[1]; sB1[14] = 0.f;
    }
    __syncthreads();
    int lin = blockIdx.x * 256 + tid;     // 5 heads x 75008 row-pairs (wave-aligned)
    int h = lin / 75008;
    int rp = lin - h * 75008;
    if (rp >= 75000) return;
    int n = rp * 2;                       // rows n, n+1
    const unsigned short* hp = hbuf + n;
    float x0 = sB1[h * 3 + 0], x1 = sB1[h * 3 + 1], x2 = sB1[h * 3 + 2];
    float y0 = x0, y1 = x1, y2 = x2;
    int cbase = h * 64;
#pragma unroll 8
    for (int cc = 0; cc < 64; ++cc) {
        int c = cbase + cc;
        unsigned raw = *(const unsigned*)(hp + (size_t)c * SROW);
        float v0 = __builtin_bit_cast(float, raw << 16);
        float v1 = __builtin_bit_cast(float, raw & 0xffff0000u);
        float sc = sScale[c], sh = sShift[c];
        v0 = fmaxf(v0 * sc + sh, 0.f);
        v1 = fmaxf(v1 * sc + sh, 0.f);
        float w0 = sW1[c * 3 + 0], w1 = sW1[c * 3 + 1], w2 = sW1[c * 3 + 2];
        x0 += v0 * w0; x1 += v0 * w1; x2 += v0 * w2;
        y0 += v1 * w0; y1 += v1 * w1; y2 += v1 * w2;
    }
    if (h == 0) {
        out[n * 3 + 0] = x0; out[n * 3 + 1] = x1; out[n * 3 + 2] = x2;
        out[(n + 1) * 3 + 0] = y0; out[(n + 1) * 3 + 1] = y1; out[(n + 1) * 3 + 2] = y2;
    } else if (h == 1) {
        out[450000 + n * 2 + 0] = x0; out[450000 + n * 2 + 1] = x1;
        out[450000 + (n + 1) * 2 + 0] = y0; out[450000 + (n + 1) * 2 + 1] = y1;
    } else if (h == 2) {
        out[750000 + n] = x0; out[750000 + n + 1] = y0;
    } else if (h == 3) {
        out[900000 + n * 3 + 0] = x0; out[900000 + n * 3 + 1] = x1; out[900000 + n * 3 + 2] = x2;
        out[900000 + (n + 1) * 3 + 0] = y0; out[900000 + (n + 1) * 3 + 1] = y1; out[900000 + (n + 1) * 3 + 2] = y2;
    } else {
        out[1350000 + n * 2 + 0] = x0; out[1350000 + n * 2 + 1] = x1;
        out[1350000 + (n + 1) * 2 + 0] = y0; out[1350000 + (n + 1) * 2 + 1] = y1;
    }
}

extern "C" void kernel_launch(void* const* d_in, const int* in_sizes, int n_in,
                              void* d_out, int out_size, void* d_ws, size_t ws_size,
                              hipStream_t stream) {
    const float* features = (const float*)d_in[0];
    const int* nbr        = (const int*)d_in[1];
    const float* w3       = (const float*)d_in[2];
    const float* gamma    = (const float*)d_in[3];
    const float* beta     = (const float*)d_in[4];
    const float* W1_0 = (const float*)d_in[5];  const float* b1_0 = (const float*)d_in[6];
    const float* W1_1 = (const float*)d_in[7];  const float* b1_1 = (const float*)d_in[8];
    const float* W1_2 = (const float*)d_in[9];  const float* b1_2 = (const float*)d_in[10];
    const float* W1_3 = (const float*)d_in[11]; const float* b1_3 = (const float*)d_in[12];
    const float* W1_4 = (const float*)d_in[13]; const float* b1_4 = (const float*)d_in[14];
    float* out = (float*)d_out;

    char* ws = (char*)d_ws;
    unsigned short* featB = (unsigned short*)ws;               // (150000+1)*64 bf16
    unsigned short* Bt    = (unsigned short*)(ws + 19200128);  // 5*64*576 bf16
    float* stats          = (float*)(ws + 19568768);           // 640 f32
    unsigned short* hbuf  = (unsigned short*)(ws + 19571328);  // 320*150016 bf16

    prep_feat<<<(NVOX * 16 + 16 + 255) / 256, 256, 0, stream>>>(features, featB);
    prep_w3<<<184320 / 256, 256, 0, stream>>>(w3, Bt, stats);
    gemm_kernel<<<8 * 5 * 74, 256, 0, stream>>>(featB, Bt, nbr, hbuf, stats);
    head_kernel<<<(5 * 75008) / 256, 256, 0, stream>>>(hbuf, stats, gamma, beta,
        W1_0, W1_1, W1_2, W1_3, W1_4, b1_0, b1_1, b1_2, b1_3, b1_4, out);
}